// Round 16
// baseline (22.657 us; speedup 1.0000x reference)
//
#include <hip/hip_runtime.h>
#include <hip/hip_bf16.h>

#define H 1024
#define B 128

typedef unsigned short u16;
typedef unsigned int u32;
typedef __attribute__((ext_vector_type(8))) short bf16x8;
typedef __attribute__((ext_vector_type(4))) float f32x4;

static __device__ inline u16 f2bf(float x) {
    __hip_bfloat16 h = __float2bfloat16(x);   // RTNE -> v_cvt_pk_bf16_f32 pairs
    return __builtin_bit_cast(u16, h);
}

// ---- k1 -------------------------------------------------------------------
// blocks 0..127 : 8 U-rows each. Q[k][j] = exp(U[k][j]) / S[k], written in
//   MFMA-B-packed layout expUP[k>>3][j][k&7] (bf16) via LDS transpose.
// blocks 128..159: 4 A-rows each -> expA[b][k] = exp(A[b][k]) bf16 row-major.
// Ends with an AGENT-scope release fence (R15 proved fences fix the graph-
// replay ws-handoff divergence; system scope cost +8.5us — agent scope
// targets the shared LLC, the actual coherence point between XCDs).
__global__ __launch_bounds__(256) void k1(const float* __restrict__ A,
                                          const float* __restrict__ U,
                                          u16* __restrict__ expUP,
                                          u16* __restrict__ expA) {
    const int t = threadIdx.x, w = t >> 6, l = t & 63;
    const int blk = blockIdx.x;
    if (blk < 128) {
        __shared__ u16 Lq[8][1024];   // 16 KB
        #pragma unroll
        for (int rr = 0; rr < 2; ++rr) {
            const int row = w * 2 + rr;                       // 0..7
            const float* Ur = U + (size_t)(blk * 8 + row) * H;
            float e[16];
            float s = 0.f;
            #pragma unroll
            for (int c = 0; c < 4; ++c) {
                float4 u4 = *reinterpret_cast<const float4*>(Ur + c * 256 + l * 4);
                e[c*4+0] = __expf(u4.x); e[c*4+1] = __expf(u4.y);
                e[c*4+2] = __expf(u4.z); e[c*4+3] = __expf(u4.w);
                s += e[c*4+0] + e[c*4+1] + e[c*4+2] + e[c*4+3];
            }
            #pragma unroll
            for (int off = 32; off > 0; off >>= 1) s += __shfl_down(s, off, 64);
            const float is = 1.0f / __shfl(s, 0, 64);
            #pragma unroll
            for (int c = 0; c < 4; ++c) {
                ushort4 o = {f2bf(e[c*4+0]*is), f2bf(e[c*4+1]*is),
                             f2bf(e[c*4+2]*is), f2bf(e[c*4+3]*is)};
                *reinterpret_cast<ushort4*>(&Lq[row][c*256 + l*4]) = o;
            }
        }
        __syncthreads();
        // packed write-out: this block owns k-group (blk) -> [1024 j][8 k]
        u16* dst = expUP + (size_t)blk * (H * 8);
        #pragma unroll
        for (int c = 0; c < 4; ++c) {
            const int j = c * 256 + t;
            uint4 v;
            v.x = (u32)Lq[0][j] | ((u32)Lq[1][j] << 16);
            v.y = (u32)Lq[2][j] | ((u32)Lq[3][j] << 16);
            v.z = (u32)Lq[4][j] | ((u32)Lq[5][j] << 16);
            v.w = (u32)Lq[6][j] | ((u32)Lq[7][j] << 16);
            *reinterpret_cast<uint4*>(dst + (size_t)j * 8) = v;
        }
    } else {
        const int b = (blk - 128) * 4 + w;
        const float* Ar = A + (size_t)b * H;
        u16* Er = expA + (size_t)b * H;
        #pragma unroll
        for (int c = 0; c < 4; ++c) {
            float4 a4 = *reinterpret_cast<const float4*>(Ar + c * 256 + l * 4);
            ushort4 o = {f2bf(__expf(a4.x)), f2bf(__expf(a4.y)),
                         f2bf(__expf(a4.z)), f2bf(__expf(a4.w))};
            *reinterpret_cast<ushort4*>(Er + c * 256 + l * 4) = o;
        }
    }
    // release: barrier drains every wave's stores (vmcnt(0) before s_barrier),
    // then one lane pushes dirty L2 lines to the LLC (agent coherence point).
    __syncthreads();
    if (t == 0) __threadfence();
}

// ---- k2: out[b][j] = log( sum_k expA[b][k] * Q[k][j] ) --------------------
// grid (8,32) = 256 blocks x 512 threads = 8 waves: kh in 0..3 (K-split),
// jh in 0..1. Pure load+MFMA K-loop: no exp, no staging, no barriers.
// Opens with an AGENT-scope acquire fence (invalidate stale clean L2 lines).
__global__ __launch_bounds__(512) void k2(const u16* __restrict__ expA,
                                          const u16* __restrict__ expUP,
                                          float* __restrict__ out) {
    __shared__ float red[4][2][4][66];   // [kh][jh][r][lane] f32, pad 66
    const int t = threadIdx.x, l = t & 63, w = t >> 6;

    if (t == 0) __threadfence();   // acquire side of the k1->k2 handoff
    __syncthreads();

    const int jh = w & 1, kh = w >> 1;
    const int b0 = blockIdx.x * 16;
    const int j0 = blockIdx.y * 32;
    const int colJ = j0 + jh * 16 + (l & 15);
    const int arow = b0 + (l & 15);
    const int kg   = l >> 4;              // 0..3

    f32x4 acc = {0.f, 0.f, 0.f, 0.f};
    #pragma unroll
    for (int s = 0; s < 8; ++s) {
        const int kk = s * 128 + kh * 32 + kg * 8;
        bf16x8 af = *reinterpret_cast<const bf16x8*>(expA + (size_t)arow * H + kk);
        bf16x8 bfv = *reinterpret_cast<const bf16x8*>(expUP + ((size_t)(kk >> 3) * H + colJ) * 8);
        acc = __builtin_amdgcn_mfma_f32_16x16x32_bf16(af, bfv, acc, 0, 0, 0);
    }

    #pragma unroll
    for (int r = 0; r < 4; ++r) red[kh][jh][r][l] = acc[r];
    __syncthreads();

    // one output per thread: row = t>>5 (0..15), c = t&31
    const int row = t >> 5, c = t & 31;
    const int jj = c >> 4, cc = c & 15;
    const int ll = (row >> 2) * 16 + cc, r = row & 3;
    const float v = red[0][jj][r][ll] + red[1][jj][r][ll]
                  + red[2][jj][r][ll] + red[3][jj][r][ll];
    out[(size_t)(b0 + row) * H + j0 + c] = __logf(v);
}

extern "C" void kernel_launch(void* const* d_in, const int* in_sizes, int n_in,
                              void* d_out, int out_size, void* d_ws, size_t ws_size,
                              hipStream_t stream) {
    const float* A = (const float*)d_in[0];   // log_alpha (128 x 1024)
    const float* U = (const float*)d_in[1];   // unnormalized_tran (1024 x 1024)
    float* out = (float*)d_out;               // (128 x 1024) f32

    char* ws = (char*)d_ws;
    u16* expUP = (u16*)ws;                        // 2 MB  packed Q bf16
    u16* expA  = (u16*)(ws + (size_t)2 * 1024 * 1024);  // 256 KB exp(A) bf16

    k1<<<160, 256, 0, stream>>>(A, U, expUP, expA);
    dim3 g(B / 16, H / 32);                   // (8, 32) = 256 blocks
    k2<<<g, 512, 0, stream>>>(expA, expUP, out);
}

// Round 17
// 16.761 us; speedup vs baseline: 1.3518x; 1.3518x over previous
//
#include <hip/hip_runtime.h>
#include <hip/hip_bf16.h>

#define H 1024
#define B 128

typedef unsigned short u16;
typedef unsigned int u32;
typedef unsigned long long u64;
typedef __attribute__((ext_vector_type(8))) short bf16x8;
typedef __attribute__((ext_vector_type(4))) float f32x4;

static __device__ inline u16 f2bf(float x) {
    __hip_bfloat16 h = __float2bfloat16(x);   // RTNE -> v_cvt_pk_bf16_f32 pairs
    return __builtin_bit_cast(u16, h);
}

// ws handoff accesses are device-scope (sc1): producer writes land in the
// shared LLC, consumer reads bypass its XCD's (possibly stale) L2. This
// replaces R15/R16's per-block __threadfence whole-L2 walks (+8.6us) with
// per-access coherence (~0 extra ops). R14 proved the handoff needs SOME
// device-scope mechanism under graph replay; R15/R16 proved fences work but
// cost; this is the cheap form.
static __device__ inline void st_agent(u16* p, u64 v) {
    __hip_atomic_store((u64*)p, v, __ATOMIC_RELAXED, __HIP_MEMORY_SCOPE_AGENT);
}
static __device__ inline u64 ld_agent(const u16* p) {
    return __hip_atomic_load((const u64*)p, __ATOMIC_RELAXED, __HIP_MEMORY_SCOPE_AGENT);
}

// ---- k1 -------------------------------------------------------------------
// blocks 0..127 : 8 U-rows each. Q[k][j] = exp(U[k][j]) / S[k], written in
//   MFMA-B-packed layout expUP[k>>3][j][k&7] (bf16) via LDS transpose.
// blocks 128..159: 4 A-rows each -> expA[b][k] = exp(A[b][k]) bf16 row-major.
__global__ __launch_bounds__(256) void k1(const float* __restrict__ A,
                                          const float* __restrict__ U,
                                          u16* __restrict__ expUP,
                                          u16* __restrict__ expA) {
    const int t = threadIdx.x, w = t >> 6, l = t & 63;
    const int blk = blockIdx.x;
    if (blk < 128) {
        __shared__ u16 Lq[8][1024];   // 16 KB
        #pragma unroll
        for (int rr = 0; rr < 2; ++rr) {
            const int row = w * 2 + rr;                       // 0..7
            const float* Ur = U + (size_t)(blk * 8 + row) * H;
            float e[16];
            float s = 0.f;
            #pragma unroll
            for (int c = 0; c < 4; ++c) {
                float4 u4 = *reinterpret_cast<const float4*>(Ur + c * 256 + l * 4);
                e[c*4+0] = __expf(u4.x); e[c*4+1] = __expf(u4.y);
                e[c*4+2] = __expf(u4.z); e[c*4+3] = __expf(u4.w);
                s += e[c*4+0] + e[c*4+1] + e[c*4+2] + e[c*4+3];
            }
            #pragma unroll
            for (int off = 32; off > 0; off >>= 1) s += __shfl_down(s, off, 64);
            const float is = 1.0f / __shfl(s, 0, 64);
            #pragma unroll
            for (int c = 0; c < 4; ++c) {
                ushort4 o = {f2bf(e[c*4+0]*is), f2bf(e[c*4+1]*is),
                             f2bf(e[c*4+2]*is), f2bf(e[c*4+3]*is)};
                *reinterpret_cast<ushort4*>(&Lq[row][c*256 + l*4]) = o;
            }
        }
        __syncthreads();
        // packed write-out: this block owns k-group (blk) -> [1024 j][8 k]
        u16* dst = expUP + (size_t)blk * (H * 8);
        #pragma unroll
        for (int c = 0; c < 4; ++c) {
            const int j = c * 256 + t;
            const u32 x = (u32)Lq[0][j] | ((u32)Lq[1][j] << 16);
            const u32 y = (u32)Lq[2][j] | ((u32)Lq[3][j] << 16);
            const u32 z = (u32)Lq[4][j] | ((u32)Lq[5][j] << 16);
            const u32 q = (u32)Lq[6][j] | ((u32)Lq[7][j] << 16);
            st_agent(dst + (size_t)j * 8,     (u64)x | ((u64)y << 32));
            st_agent(dst + (size_t)j * 8 + 4, (u64)z | ((u64)q << 32));
        }
    } else {
        const int b = (blk - 128) * 4 + w;
        const float* Ar = A + (size_t)b * H;
        u16* Er = expA + (size_t)b * H;
        #pragma unroll
        for (int c = 0; c < 4; ++c) {
            float4 a4 = *reinterpret_cast<const float4*>(Ar + c * 256 + l * 4);
            ushort4 o = {f2bf(__expf(a4.x)), f2bf(__expf(a4.y)),
                         f2bf(__expf(a4.z)), f2bf(__expf(a4.w))};
            st_agent(Er + c * 256 + l * 4, __builtin_bit_cast(u64, o));
        }
    }
}

// ---- k2: out[b][j] = log( sum_k expA[b][k] * Q[k][j] ) --------------------
// grid (8,32) = 256 blocks x 512 threads = 8 waves: kh in 0..3 (K-split),
// jh in 0..1. Pure load+MFMA K-loop: no exp, no staging, no barriers.
__global__ __launch_bounds__(512) void k2(const u16* __restrict__ expA,
                                          const u16* __restrict__ expUP,
                                          float* __restrict__ out) {
    __shared__ float red[4][2][4][66];   // [kh][jh][r][lane] f32, pad 66
    const int t = threadIdx.x, l = t & 63, w = t >> 6;
    const int jh = w & 1, kh = w >> 1;
    const int b0 = blockIdx.x * 16;
    const int j0 = blockIdx.y * 32;
    const int colJ = j0 + jh * 16 + (l & 15);
    const int arow = b0 + (l & 15);
    const int kg   = l >> 4;              // 0..3

    f32x4 acc = {0.f, 0.f, 0.f, 0.f};
    #pragma unroll
    for (int s = 0; s < 8; ++s) {
        const int kk = s * 128 + kh * 32 + kg * 8;
        const u16* ap = expA + (size_t)arow * H + kk;
        const u16* bp = expUP + ((size_t)(kk >> 3) * H + colJ) * 8;
        const u64 alo = ld_agent(ap), ahi = ld_agent(ap + 4);
        const u64 blo = ld_agent(bp), bhi = ld_agent(bp + 4);
        uint4 aw = {(u32)alo, (u32)(alo >> 32), (u32)ahi, (u32)(ahi >> 32)};
        uint4 bw = {(u32)blo, (u32)(blo >> 32), (u32)bhi, (u32)(bhi >> 32)};
        acc = __builtin_amdgcn_mfma_f32_16x16x32_bf16(
            __builtin_bit_cast(bf16x8, aw), __builtin_bit_cast(bf16x8, bw),
            acc, 0, 0, 0);
    }

    #pragma unroll
    for (int r = 0; r < 4; ++r) red[kh][jh][r][l] = acc[r];
    __syncthreads();

    // one output per thread: row = t>>5 (0..15), c = t&31
    const int row = t >> 5, c = t & 31;
    const int jj = c >> 4, cc = c & 15;
    const int ll = (row >> 2) * 16 + cc, r = row & 3;
    const float v = red[0][jj][r][ll] + red[1][jj][r][ll]
                  + red[2][jj][r][ll] + red[3][jj][r][ll];
    out[(size_t)(b0 + row) * H + j0 + c] = __logf(v);
}

extern "C" void kernel_launch(void* const* d_in, const int* in_sizes, int n_in,
                              void* d_out, int out_size, void* d_ws, size_t ws_size,
                              hipStream_t stream) {
    const float* A = (const float*)d_in[0];   // log_alpha (128 x 1024)
    const float* U = (const float*)d_in[1];   // unnormalized_tran (1024 x 1024)
    float* out = (float*)d_out;               // (128 x 1024) f32

    char* ws = (char*)d_ws;
    u16* expUP = (u16*)ws;                        // 2 MB  packed Q bf16
    u16* expA  = (u16*)(ws + (size_t)2 * 1024 * 1024);  // 256 KB exp(A) bf16

    k1<<<160, 256, 0, stream>>>(A, U, expUP, expA);
    dim3 g(B / 16, H / 32);                   // (8, 32) = 256 blocks
    k2<<<g, 512, 0, stream>>>(expA, expUP, out);
}